// Round 5
// baseline (262.928 us; speedup 1.0000x reference)
//
#include <hip/hip_runtime.h>
#include <stdint.h>

#define N_ROWS   16384
#define IN_DIM   512
#define CB_DIM   16
#define CB_VOCAB 8192

// ---- front geometry
#define PROJ_BLOCKS 1024                         // 1 row-tile each, 4-wave split-K
#define PREP_BLOCKS 128                          // 4 code-tiles each + part/cnt zero

// ---- scan geometry
#define N_CT   (CB_VOCAB / 16)                   // 512 code-tiles
#define CODEPARTS 32
#define CT_PER_PART (N_CT / CODEPARTS)           // 16
#define N_ROWGRP 64                              // 256 rows per rowgrp

// ---- workspace layout (bytes), ~3.2 MB
#define WS_OFF_AFA  0                            // A-frag [A1|A2]: 1 MB
#define WS_OFF_AFB  (1u << 20)                   // A-frag [A1|A3]: 1 MB
#define WS_OFF_BHH  (2u << 20)                   // B-frag [B1;B2]: 512 KB
#define WS_OFF_B31  ((2u << 20) + (512u << 10))  // B-frag [B3;B1]: 512 KB
#define WS_OFF_PART (3u << 20)                   // u64[16384]: 128 KB
#define WS_OFF_CNT  ((3u << 20) + (128u << 10))  // u32[64]

typedef __attribute__((ext_vector_type(8))) short bf16x8;
typedef __attribute__((ext_vector_type(4))) float f32x4;

// monotone float -> uint32 key (order-preserving)
__device__ __forceinline__ unsigned fkey(float f) {
    unsigned u = __float_as_uint(f);
    return (u & 0x80000000u) ? ~u : (u | 0x80000000u);
}

// fp32 -> bf16 bits, round-to-nearest-even
__device__ __forceinline__ unsigned short f2bf(float f) {
    unsigned u = __float_as_uint(f);
    return (unsigned short)((u + 0x7FFFu + ((u >> 16) & 1u)) >> 16);
}
__device__ __forceinline__ float bf2f(unsigned short h) {
    return __uint_as_float(((unsigned)h) << 16);
}

// ---------------- K1: MFMA projection (blocks 0..1023) + prep (1024..1151) --
// R4 post-mortem: k_proj at grid 256 = 1 block/CU = 1 wave/SIMD -- zero
// latency hiding, ~20+ us for a 7 us job. Fix: split-K. Block = 1 row-tile;
// wave w computes a K=128 partial (chunks 4w..4w+3, 6 MFMAs each), partials
// folded through a 4 KB LDS buffer. Each block builds the 48 KB P-frag
// table in its OWN LDS from P (32 KB, L2-broadcast-hot after first blocks),
// removing the k_prep->k_proj ordering dependency; prep (CB B-frags +
// part/cnt zero) rides along as extra blocks -> one dispatch saved.
// LDS 52 KB -> 3 blocks/CU = 12 waves/CU; x floor 5.1 us now hideable.
__global__ __launch_bounds__(256, 3)
void k_front(const float* __restrict__ x, const float* __restrict__ P,
             const float* __restrict__ CB,
             bf16x8* __restrict__ AfragA, bf16x8* __restrict__ AfragB,
             bf16x8* __restrict__ Bhh, bf16x8* __restrict__ B31,
             unsigned long long* __restrict__ part, unsigned* __restrict__ cnt) {
    __shared__ bf16x8 sPf[3][1024];              // P-frags, 3 levels: 48 KB
    __shared__ __align__(16) float foldb[1024];  // split-K fold / transpose: 4 KB

    const int tid  = threadIdx.x;
    const int wave = tid >> 6;
    const int lane = tid & 63;

    if (blockIdx.x >= PROJ_BLOCKS) {
        // ---- prep path: zero part/cnt, build CB B-frags ----
        const int pb = blockIdx.x - PROJ_BLOCKS;
        if (tid < 128) part[pb * 128 + tid] = 0ull;
        if (pb == 0 && tid < 64) cnt[tid] = 0u;

        const int ct   = pb * 4 + wave;
        const int n    = lane & 15;
        const int quad = lane >> 4;
        const int kh   = (quad & 1) * 8;
        const int lvl  = quad >> 1;
        const int code = ct * 16 + n;

        const float4* b4 = (const float4*)(CB + (size_t)code * CB_DIM + kh);
        float4 a = b4[0], b = b4[1];
        float v[8] = {a.x, a.y, a.z, a.w, b.x, b.y, b.z, b.w};

        bf16x8 shh, s31;
#pragma unroll
        for (int j = 0; j < 8; ++j) {
            float f = v[j];
            unsigned short b1 = f2bf(f);  float r1 = f - bf2f(b1);
            unsigned short b2 = f2bf(r1); float r2 = r1 - bf2f(b2);
            unsigned short b3 = f2bf(r2);
            shh[j] = (short)(lvl ? b2 : b1);
            s31[j] = (short)(lvl ? b1 : b3);
        }
        Bhh[(size_t)ct * 64 + lane] = shh;
        B31[(size_t)ct * 64 + lane] = s31;
        return;
    }

    // ---- Phase A: build P-frags in LDS (slot = chunk*64 + fraglane) ----
#pragma unroll
    for (int s4 = 0; s4 < 4; ++s4) {
        const int s  = tid + s4 * 256;
        const int c  = s >> 6;
        const int l  = s & 63;
        const int n  = l & 15;
        const int kq = l >> 4;
        const int k0 = c * 32 + kq * 8;

        bf16x8 p1, p2, p3;
#pragma unroll
        for (int j = 0; j < 8; ++j) {
            float f = P[(size_t)(k0 + j) * CB_DIM + n];
            unsigned short b1 = f2bf(f);  float r1 = f - bf2f(b1);
            unsigned short b2 = f2bf(r1); float r2 = r1 - bf2f(b2);
            unsigned short b3 = f2bf(r2);
            p1[j] = (short)b1; p2[j] = (short)b2; p3[j] = (short)b3;
        }
        sPf[0][s] = p1; sPf[1][s] = p2; sPf[2][s] = p3;
    }
    __syncthreads();

    // ---- Phase B: split-K proj; wave w covers chunks 4w..4w+3 ----
    const int rt = blockIdx.x;
    const int m  = lane & 15;
    const int kq = lane >> 4;
    const float4* xr = (const float4*)(x + (size_t)(rt * 16 + m) * IN_DIM);

    float4 xf[8];                                // all 8 x-loads issued upfront
#pragma unroll
    for (int i = 0; i < 4; ++i) {
        xf[2 * i]     = xr[(wave * 4 + i) * 8 + kq * 2];
        xf[2 * i + 1] = xr[(wave * 4 + i) * 8 + kq * 2 + 1];
    }

    f32x4 acc1 = {0.f, 0.f, 0.f, 0.f};
    f32x4 acc2 = {0.f, 0.f, 0.f, 0.f};

#pragma unroll
    for (int i = 0; i < 4; ++i) {
        const int c = wave * 4 + i;
        bf16x8 p1 = sPf[0][c * 64 + lane];
        bf16x8 p2 = sPf[1][c * 64 + lane];
        bf16x8 p3 = sPf[2][c * 64 + lane];

        float4 xa = xf[2 * i], xb = xf[2 * i + 1];
        float xs[8] = {xa.x, xa.y, xa.z, xa.w, xb.x, xb.y, xb.z, xb.w};
        bf16x8 a1, a2, a3;
#pragma unroll
        for (int j = 0; j < 8; ++j) {
            float f = xs[j];
            unsigned short b1 = f2bf(f);  float r1 = f - bf2f(b1);
            unsigned short b2 = f2bf(r1); float r2 = r1 - bf2f(b2);
            unsigned short b3 = f2bf(r2);
            a1[j] = (short)b1; a2[j] = (short)b2; a3[j] = (short)b3;
        }

        // terms i+j<=4: (1,1)(2,1)(2,2) chain1; (1,2)(1,3)(3,1) chain2
        acc1 = __builtin_amdgcn_mfma_f32_16x16x32_bf16(a1, p1, acc1, 0, 0, 0);
        acc2 = __builtin_amdgcn_mfma_f32_16x16x32_bf16(a1, p2, acc2, 0, 0, 0);
        acc1 = __builtin_amdgcn_mfma_f32_16x16x32_bf16(a2, p1, acc1, 0, 0, 0);
        acc2 = __builtin_amdgcn_mfma_f32_16x16x32_bf16(a1, p3, acc2, 0, 0, 0);
        acc1 = __builtin_amdgcn_mfma_f32_16x16x32_bf16(a2, p2, acc1, 0, 0, 0);
        acc2 = __builtin_amdgcn_mfma_f32_16x16x32_bf16(a3, p1, acc2, 0, 0, 0);
    }

    *(f32x4*)&foldb[(wave * 64 + lane) * 4] = acc1 + acc2;
    __syncthreads();

    // ---- Phase C (wave 0): fold partials, transpose, split, store ----
    if (wave == 0) {
        f32x4 s0 = *(const f32x4*)&foldb[(0 * 64 + lane) * 4];
        f32x4 s1 = *(const f32x4*)&foldb[(1 * 64 + lane) * 4];
        f32x4 s2 = *(const f32x4*)&foldb[(2 * 64 + lane) * 4];
        f32x4 s3 = *(const f32x4*)&foldb[(3 * 64 + lane) * 4];
        f32x4 sum = ((s0 + s1) + s2) + s3;

        // reads must retire before we overwrite foldb (rule 18 fence)
        asm volatile("s_waitcnt lgkmcnt(0)" ::: "memory");
        __builtin_amdgcn_sched_barrier(0);

        // C layout: lane holds xp[row=(kq*4+r)][col=m] -> transpose [16][20]
#pragma unroll
        for (int r = 0; r < 4; ++r)
            foldb[(kq * 4 + r) * 20 + m] = sum[r];

        asm volatile("s_waitcnt lgkmcnt(0)" ::: "memory");
        __builtin_amdgcn_sched_barrier(0);

        const int kh  = (kq & 1) * 8;
        const int lvl = kq >> 1;
        bf16x8 sa, sb;
#pragma unroll
        for (int j = 0; j < 8; ++j) {
            float f = foldb[m * 20 + kh + j];
            unsigned short b1 = f2bf(f);  float r1 = f - bf2f(b1);
            unsigned short b2 = f2bf(r1); float r2 = r1 - bf2f(b2);
            unsigned short b3 = f2bf(r2);
            sa[j] = (short)(lvl ? b2 : b1);
            sb[j] = (short)(lvl ? b3 : b1);
        }
        AfragA[(size_t)rt * 64 + lane] = sa;
        AfragB[(size_t)rt * 64 + lane] = sb;
    }
}

// ---------------- K2: MFMA sim + argmax + last-block finalize ---------------
// grid 2048 = 64 rowgrps x 32 codeparts; wave = 4 row-tiles x 16 code-tiles.
// R4 counters: 50 us, FETCH 8.8 MB (not memory-bound), MfmaUtil 20 /
// VALUBusy 42 / Occ 32 -- latency-bound on the 3 per-iter L1/L2 loads
// (1-deep prefetch: ~150 cyc of work between issue and use vs ~250 cyc
// latency) + per-iter 64-bit address recompute. Fix: fully unroll the
// 16-iter loop, 2-deep register prefetch (static [c&1] indexing under full
// unroll -- rule 20), pointer+immediate addressing, hoisted zero-C.
// ~100 VGPR -> 4-5 waves/SIMD, but each wave is now nearly self-sufficient.
__global__ __launch_bounds__(256, 4)
void k_scan(const bf16x8* __restrict__ AfragA, const bf16x8* __restrict__ AfragB,
            const bf16x8* __restrict__ Bhh, const bf16x8* __restrict__ B31,
            unsigned long long* __restrict__ part, unsigned* __restrict__ cnt,
            int* __restrict__ out) {
    __shared__ int s_done;
    const int codepart = blockIdx.x & (CODEPARTS - 1);
    const int rowgrp   = blockIdx.x >> 5;
    const int wave     = threadIdx.x >> 6;
    const int lane     = threadIdx.x & 63;
    const int n        = lane & 15;
    const int quad     = lane >> 4;
    const int rt_base  = rowgrp * 16 + wave * 4;

    bf16x8 Aa[4], Ab[4];
#pragma unroll
    for (int t = 0; t < 4; ++t) {
        Aa[t] = AfragA[(size_t)(rt_base + t) * 64 + lane];
        Ab[t] = AfragB[(size_t)(rt_base + t) * 64 + lane];
    }

    float bestv[4][4];
    int   bestc[4][4];
#pragma unroll
    for (int t = 0; t < 4; ++t)
#pragma unroll
        for (int r = 0; r < 4; ++r) { bestv[t][r] = -INFINITY; bestc[t][r] = 0; }

    const int ct0 = codepart * CT_PER_PART;
    const bf16x8* pB1  = Bhh + (size_t)ct0 * 64 + lane;
    const bf16x8* pB1s = Bhh + (size_t)ct0 * 64 + (lane ^ 32);
    const bf16x8* pB3  = B31 + (size_t)ct0 * 64 + lane;

    const f32x4 zero = {0.f, 0.f, 0.f, 0.f};

    bf16x8 rb1[2], rb1s[2], rb3[2];              // 2-deep prefetch ring
    rb1[0]  = pB1[0];   rb1[1]  = pB1[64];
    rb1s[0] = pB1s[0];  rb1s[1] = pB1s[64];
    rb3[0]  = pB3[0];   rb3[1]  = pB3[64];

#pragma unroll
    for (int c = 0; c < CT_PER_PART; ++c) {
        bf16x8 b1 = rb1[c & 1], b1s = rb1s[c & 1], b3 = rb3[c & 1];
        if (c + 2 < CT_PER_PART) {
            rb1[c & 1]  = pB1[(c + 2) * 64];
            rb1s[c & 1] = pB1s[(c + 2) * 64];
            rb3[c & 1]  = pB3[(c + 2) * 64];
        }
#pragma unroll
        for (int t = 0; t < 4; ++t) {
            f32x4 s = __builtin_amdgcn_mfma_f32_16x16x32_bf16(Aa[t], b1, zero, 0, 0, 0);
            s = __builtin_amdgcn_mfma_f32_16x16x32_bf16(Aa[t], b1s, s, 0, 0, 0);
            s = __builtin_amdgcn_mfma_f32_16x16x32_bf16(Ab[t], b3,  s, 0, 0, 0);
#pragma unroll
            for (int r = 0; r < 4; ++r) {
                if (s[r] > bestv[t][r]) { bestv[t][r] = s[r]; bestc[t][r] = c; }
            }
        }
    }

    // reduce over the 16 code-class lanes, then device-scope max per row
#pragma unroll
    for (int t = 0; t < 4; ++t) {
#pragma unroll
        for (int r = 0; r < 4; ++r) {
            unsigned code = (unsigned)(codepart * (CT_PER_PART * 16) +
                                       bestc[t][r] * 16 + n);
            unsigned long long packed =
                ((unsigned long long)fkey(bestv[t][r]) << 32) |
                (unsigned long long)(0xFFFFFFFFu - code);
#pragma unroll
            for (int mk = 1; mk <= 8; mk <<= 1) {
                unsigned long long o = __shfl_xor(packed, mk, 64);
                packed = (o > packed) ? o : packed;
            }
            if (n == 0) {
                int row = (rt_base + t) * 16 + quad * 4 + r;
                atomicMax(&part[row], packed);
            }
        }
    }

    // __syncthreads drains vmcnt -> all this block's atomics are complete
    __syncthreads();
    if (threadIdx.x == 0)
        s_done = (atomicAdd(&cnt[rowgrp], 1u) == (unsigned)(CODEPARTS - 1));
    __syncthreads();

    if (s_done) {
        int row = rowgrp * 256 + threadIdx.x;
        unsigned long long v = atomicAdd(&part[row], 0ull);   // coherent read
        out[row] = (int)(0xFFFFFFFFu - (unsigned)(v & 0xFFFFFFFFull));
    }
}

extern "C" void kernel_launch(void* const* d_in, const int* in_sizes, int n_in,
                              void* d_out, int out_size, void* d_ws, size_t ws_size,
                              hipStream_t stream) {
    const float* x  = (const float*)d_in[0];   // [16384, 512]
    const float* P  = (const float*)d_in[1];   // [512, 16]
    const float* CB = (const float*)d_in[2];   // [8192, 16]
    int* out = (int*)d_out;                    // [16384] int32

    char* ws = (char*)d_ws;
    bf16x8* AfragA = (bf16x8*)(ws + WS_OFF_AFA);
    bf16x8* AfragB = (bf16x8*)(ws + WS_OFF_AFB);
    bf16x8* Bhh    = (bf16x8*)(ws + WS_OFF_BHH);
    bf16x8* B31    = (bf16x8*)(ws + WS_OFF_B31);
    unsigned long long* part = (unsigned long long*)(ws + WS_OFF_PART);
    unsigned* cnt  = (unsigned*)(ws + WS_OFF_CNT);

    k_front<<<PROJ_BLOCKS + PREP_BLOCKS, 256, 0, stream>>>(
        x, P, CB, AfragA, AfragB, Bhh, B31, part, cnt);            // 1152 blocks
    k_scan<<<N_ROWGRP * CODEPARTS, 256, 0, stream>>>(
        AfragA, AfragB, Bhh, B31, part, cnt, out);                 // 2048 blocks
}

// Round 6
// 117.914 us; speedup vs baseline: 2.2298x; 2.2298x over previous
//
#include <hip/hip_runtime.h>
#include <stdint.h>

#define N_ROWS   16384
#define IN_DIM   512
#define CB_DIM   16
#define CB_VOCAB 8192

// ---- front geometry
#define PROJ_BLOCKS 1024                         // 1 row-tile each, 4-wave split-K
#define PREP_BLOCKS 128                          // 4 code-tiles each + part/cnt zero

// ---- scan geometry (R0's measured-38.8us shape)
#define N_CT   (CB_VOCAB / 16)                   // 512 code-tiles
#define CODEPARTS 16
#define CT_PER_PART (N_CT / CODEPARTS)           // 32
#define N_ROWGRP 64                              // 256 rows per rowgrp

// ---- workspace layout (bytes), ~3.2 MB
#define WS_OFF_AFA  0                            // A-frag [A1|A2]: 1 MB
#define WS_OFF_AFB  (1u << 20)                   // A-frag [A1|A3]: 1 MB
#define WS_OFF_BHH  (2u << 20)                   // B-frag [B1;B2]: 512 KB
#define WS_OFF_B31  ((2u << 20) + (512u << 10))  // B-frag [B3;B1]: 512 KB
#define WS_OFF_PART (3u << 20)                   // u64[16384]: 128 KB
#define WS_OFF_CNT  ((3u << 20) + (128u << 10))  // u32[64]

typedef __attribute__((ext_vector_type(8))) short bf16x8;
typedef __attribute__((ext_vector_type(4))) float f32x4;

// monotone float -> uint32 key (order-preserving)
__device__ __forceinline__ unsigned fkey(float f) {
    unsigned u = __float_as_uint(f);
    return (u & 0x80000000u) ? ~u : (u | 0x80000000u);
}

// fp32 -> bf16 bits, round-to-nearest-even
__device__ __forceinline__ unsigned short f2bf(float f) {
    unsigned u = __float_as_uint(f);
    return (unsigned short)((u + 0x7FFFu + ((u >> 16) & 1u)) >> 16);
}
__device__ __forceinline__ float bf2f(unsigned short h) {
    return __uint_as_float(((unsigned)h) << 16);
}

// ---------------- K1: MFMA projection (blocks 0..1023) + prep (1024..1151) --
// (unchanged from R5 -- not in top-5, i.e. fast)
// Block = 1 row-tile; wave w computes a K=128 partial (chunks 4w..4w+3,
// 6 MFMAs each), partials folded through a 4 KB LDS buffer. Each block
// builds the 48 KB P-frag table in its own LDS from P (L2-broadcast-hot);
// prep (CB B-frags + part/cnt zero) rides along as extra blocks.
// LDS 52 KB -> 3 blocks/CU = 12 waves/CU.
__global__ __launch_bounds__(256, 3)
void k_front(const float* __restrict__ x, const float* __restrict__ P,
             const float* __restrict__ CB,
             bf16x8* __restrict__ AfragA, bf16x8* __restrict__ AfragB,
             bf16x8* __restrict__ Bhh, bf16x8* __restrict__ B31,
             unsigned long long* __restrict__ part, unsigned* __restrict__ cnt) {
    __shared__ bf16x8 sPf[3][1024];              // P-frags, 3 levels: 48 KB
    __shared__ __align__(16) float foldb[1024];  // split-K fold / transpose: 4 KB

    const int tid  = threadIdx.x;
    const int wave = tid >> 6;
    const int lane = tid & 63;

    if (blockIdx.x >= PROJ_BLOCKS) {
        // ---- prep path: zero part/cnt, build CB B-frags ----
        const int pb = blockIdx.x - PROJ_BLOCKS;
        if (tid < 128) part[pb * 128 + tid] = 0ull;
        if (pb == 0 && tid < 64) cnt[tid] = 0u;

        const int ct   = pb * 4 + wave;
        const int n    = lane & 15;
        const int quad = lane >> 4;
        const int kh   = (quad & 1) * 8;
        const int lvl  = quad >> 1;
        const int code = ct * 16 + n;

        const float4* b4 = (const float4*)(CB + (size_t)code * CB_DIM + kh);
        float4 a = b4[0], b = b4[1];
        float v[8] = {a.x, a.y, a.z, a.w, b.x, b.y, b.z, b.w};

        bf16x8 shh, s31;
#pragma unroll
        for (int j = 0; j < 8; ++j) {
            float f = v[j];
            unsigned short b1 = f2bf(f);  float r1 = f - bf2f(b1);
            unsigned short b2 = f2bf(r1); float r2 = r1 - bf2f(b2);
            unsigned short b3 = f2bf(r2);
            shh[j] = (short)(lvl ? b2 : b1);
            s31[j] = (short)(lvl ? b1 : b3);
        }
        Bhh[(size_t)ct * 64 + lane] = shh;
        B31[(size_t)ct * 64 + lane] = s31;
        return;
    }

    // ---- Phase A: build P-frags in LDS (slot = chunk*64 + fraglane) ----
#pragma unroll
    for (int s4 = 0; s4 < 4; ++s4) {
        const int s  = tid + s4 * 256;
        const int c  = s >> 6;
        const int l  = s & 63;
        const int n  = l & 15;
        const int kq = l >> 4;
        const int k0 = c * 32 + kq * 8;

        bf16x8 p1, p2, p3;
#pragma unroll
        for (int j = 0; j < 8; ++j) {
            float f = P[(size_t)(k0 + j) * CB_DIM + n];
            unsigned short b1 = f2bf(f);  float r1 = f - bf2f(b1);
            unsigned short b2 = f2bf(r1); float r2 = r1 - bf2f(b2);
            unsigned short b3 = f2bf(r2);
            p1[j] = (short)b1; p2[j] = (short)b2; p3[j] = (short)b3;
        }
        sPf[0][s] = p1; sPf[1][s] = p2; sPf[2][s] = p3;
    }
    __syncthreads();

    // ---- Phase B: split-K proj; wave w covers chunks 4w..4w+3 ----
    const int rt = blockIdx.x;
    const int m  = lane & 15;
    const int kq = lane >> 4;
    const float4* xr = (const float4*)(x + (size_t)(rt * 16 + m) * IN_DIM);

    float4 xf[8];                                // all 8 x-loads issued upfront
#pragma unroll
    for (int i = 0; i < 4; ++i) {
        xf[2 * i]     = xr[(wave * 4 + i) * 8 + kq * 2];
        xf[2 * i + 1] = xr[(wave * 4 + i) * 8 + kq * 2 + 1];
    }

    f32x4 acc1 = {0.f, 0.f, 0.f, 0.f};
    f32x4 acc2 = {0.f, 0.f, 0.f, 0.f};

#pragma unroll
    for (int i = 0; i < 4; ++i) {
        const int c = wave * 4 + i;
        bf16x8 p1 = sPf[0][c * 64 + lane];
        bf16x8 p2 = sPf[1][c * 64 + lane];
        bf16x8 p3 = sPf[2][c * 64 + lane];

        float4 xa = xf[2 * i], xb = xf[2 * i + 1];
        float xs[8] = {xa.x, xa.y, xa.z, xa.w, xb.x, xb.y, xb.z, xb.w};
        bf16x8 a1, a2, a3;
#pragma unroll
        for (int j = 0; j < 8; ++j) {
            float f = xs[j];
            unsigned short b1 = f2bf(f);  float r1 = f - bf2f(b1);
            unsigned short b2 = f2bf(r1); float r2 = r1 - bf2f(b2);
            unsigned short b3 = f2bf(r2);
            a1[j] = (short)b1; a2[j] = (short)b2; a3[j] = (short)b3;
        }

        // terms i+j<=4: (1,1)(2,1)(2,2) chain1; (1,2)(1,3)(3,1) chain2
        acc1 = __builtin_amdgcn_mfma_f32_16x16x32_bf16(a1, p1, acc1, 0, 0, 0);
        acc2 = __builtin_amdgcn_mfma_f32_16x16x32_bf16(a1, p2, acc2, 0, 0, 0);
        acc1 = __builtin_amdgcn_mfma_f32_16x16x32_bf16(a2, p1, acc1, 0, 0, 0);
        acc2 = __builtin_amdgcn_mfma_f32_16x16x32_bf16(a1, p3, acc2, 0, 0, 0);
        acc1 = __builtin_amdgcn_mfma_f32_16x16x32_bf16(a2, p2, acc1, 0, 0, 0);
        acc2 = __builtin_amdgcn_mfma_f32_16x16x32_bf16(a3, p1, acc2, 0, 0, 0);
    }

    *(f32x4*)&foldb[(wave * 64 + lane) * 4] = acc1 + acc2;
    __syncthreads();

    // ---- Phase C (wave 0): fold partials, transpose, split, store ----
    if (wave == 0) {
        f32x4 s0 = *(const f32x4*)&foldb[(0 * 64 + lane) * 4];
        f32x4 s1 = *(const f32x4*)&foldb[(1 * 64 + lane) * 4];
        f32x4 s2 = *(const f32x4*)&foldb[(2 * 64 + lane) * 4];
        f32x4 s3 = *(const f32x4*)&foldb[(3 * 64 + lane) * 4];
        f32x4 sum = ((s0 + s1) + s2) + s3;

        // reads must retire before we overwrite foldb (rule 18 fence)
        asm volatile("s_waitcnt lgkmcnt(0)" ::: "memory");
        __builtin_amdgcn_sched_barrier(0);

        // C layout: lane holds xp[row=(kq*4+r)][col=m] -> transpose [16][20]
#pragma unroll
        for (int r = 0; r < 4; ++r)
            foldb[(kq * 4 + r) * 20 + m] = sum[r];

        asm volatile("s_waitcnt lgkmcnt(0)" ::: "memory");
        __builtin_amdgcn_sched_barrier(0);

        const int kh  = (kq & 1) * 8;
        const int lvl = kq >> 1;
        bf16x8 sa, sb;
#pragma unroll
        for (int j = 0; j < 8; ++j) {
            float f = foldb[m * 20 + kh + j];
            unsigned short b1 = f2bf(f);  float r1 = f - bf2f(b1);
            unsigned short b2 = f2bf(r1); float r2 = r1 - bf2f(b2);
            unsigned short b3 = f2bf(r2);
            sa[j] = (short)(lvl ? b2 : b1);
            sb[j] = (short)(lvl ? b3 : b1);
        }
        AfragA[(size_t)rt * 64 + lane] = sa;
        AfragB[(size_t)rt * 64 + lane] = sb;
    }
}

// ---------------- K2: MFMA sim + argmax + last-block finalize ---------------
// R5 post-mortem: the "full unroll + rb[c&1] ring" violated rule 20 (compiler
// declined the unroll -> runtime-indexed arrays -> 750 MB scratch, 224 us).
// R6: back to R0's measured-38.8us geometry (1024 blocks = 64 rowgrps x 16
// codeparts, wave = 4rt x 32ct), with ONE surgical change: depth-2 prefetch
// using NAMED scalars only (hand-unrolled c-step of 2, explicit register
// recycle, no arrays, no unroll pragma on the outer loop). Issue-to-use
// distance ~235 -> ~470 SIMD-cyc, covering L2 latency (~200-300 cyc).
__global__ __launch_bounds__(256, 4)
void k_scan(const bf16x8* __restrict__ AfragA, const bf16x8* __restrict__ AfragB,
            const bf16x8* __restrict__ Bhh, const bf16x8* __restrict__ B31,
            unsigned long long* __restrict__ part, unsigned* __restrict__ cnt,
            int* __restrict__ out) {
    __shared__ int s_done;
    const int codepart = blockIdx.x & (CODEPARTS - 1);
    const int rowgrp   = blockIdx.x >> 4;
    const int wave     = threadIdx.x >> 6;
    const int lane     = threadIdx.x & 63;
    const int n        = lane & 15;
    const int quad     = lane >> 4;
    const int rt_base  = rowgrp * 16 + wave * 4;

    bf16x8 Aa[4], Ab[4];
#pragma unroll
    for (int t = 0; t < 4; ++t) {
        Aa[t] = AfragA[(size_t)(rt_base + t) * 64 + lane];
        Ab[t] = AfragB[(size_t)(rt_base + t) * 64 + lane];
    }

    float bestv[4][4];
    int   bestc[4][4];
#pragma unroll
    for (int t = 0; t < 4; ++t)
#pragma unroll
        for (int r = 0; r < 4; ++r) { bestv[t][r] = -INFINITY; bestc[t][r] = 0; }

    const int ct0 = codepart * CT_PER_PART;
    const bf16x8* p1l  = Bhh + (size_t)ct0 * 64 + lane;
    const bf16x8* p1s  = Bhh + (size_t)ct0 * 64 + (lane ^ 32);
    const bf16x8* p3l  = B31 + (size_t)ct0 * 64 + lane;

    // depth-2 prefetch, named regs only (rule 20)
    bf16x8 c1 = p1l[0],  c1s = p1s[0],  c3 = p3l[0];    // tile c
    bf16x8 d1 = p1l[64], d1s = p1s[64], d3 = p3l[64];   // tile c+1

#define PROC(B1, B1S, B3, CIDX)                                               \
    do {                                                                      \
        _Pragma("unroll")                                                     \
        for (int t = 0; t < 4; ++t) {                                         \
            f32x4 s = __builtin_amdgcn_mfma_f32_16x16x32_bf16(                \
                          Aa[t], (B1), (f32x4){0.f, 0.f, 0.f, 0.f}, 0, 0, 0); \
            s = __builtin_amdgcn_mfma_f32_16x16x32_bf16(Aa[t], (B1S), s,      \
                                                        0, 0, 0);             \
            s = __builtin_amdgcn_mfma_f32_16x16x32_bf16(Ab[t], (B3), s,       \
                                                        0, 0, 0);             \
            _Pragma("unroll")                                                 \
            for (int r = 0; r < 4; ++r) {                                     \
                if (s[r] > bestv[t][r]) {                                     \
                    bestv[t][r] = s[r];                                       \
                    bestc[t][r] = (CIDX);                                     \
                }                                                             \
            }                                                                 \
        }                                                                     \
    } while (0)

    for (int c = 0; c < CT_PER_PART; c += 2) {
        bf16x8 e1, e1s, e3, f1, f1s, f3;
        const bool more = (c + 2 < CT_PER_PART);
        if (more) {
            e1 = p1l[(c + 2) * 64]; e1s = p1s[(c + 2) * 64]; e3 = p3l[(c + 2) * 64];
            f1 = p1l[(c + 3) * 64]; f1s = p1s[(c + 3) * 64]; f3 = p3l[(c + 3) * 64];
        }
        PROC(c1, c1s, c3, c);
        PROC(d1, d1s, d3, c + 1);
        if (more) {
            c1 = e1; c1s = e1s; c3 = e3;
            d1 = f1; d1s = f1s; d3 = f3;
        }
    }
#undef PROC

    // reduce over the 16 code-class lanes, then device-scope max per row
#pragma unroll
    for (int t = 0; t < 4; ++t) {
#pragma unroll
        for (int r = 0; r < 4; ++r) {
            unsigned code = (unsigned)(codepart * (CT_PER_PART * 16) +
                                       bestc[t][r] * 16 + n);
            unsigned long long packed =
                ((unsigned long long)fkey(bestv[t][r]) << 32) |
                (unsigned long long)(0xFFFFFFFFu - code);
#pragma unroll
            for (int mk = 1; mk <= 8; mk <<= 1) {
                unsigned long long o = __shfl_xor(packed, mk, 64);
                packed = (o > packed) ? o : packed;
            }
            if (n == 0) {
                int row = (rt_base + t) * 16 + quad * 4 + r;
                atomicMax(&part[row], packed);
            }
        }
    }

    // __syncthreads drains vmcnt -> all this block's atomics are complete
    __syncthreads();
    if (threadIdx.x == 0)
        s_done = (atomicAdd(&cnt[rowgrp], 1u) == (unsigned)(CODEPARTS - 1));
    __syncthreads();

    if (s_done) {
        int row = rowgrp * 256 + threadIdx.x;
        unsigned long long v = atomicAdd(&part[row], 0ull);   // coherent read
        out[row] = (int)(0xFFFFFFFFu - (unsigned)(v & 0xFFFFFFFFull));
    }
}

extern "C" void kernel_launch(void* const* d_in, const int* in_sizes, int n_in,
                              void* d_out, int out_size, void* d_ws, size_t ws_size,
                              hipStream_t stream) {
    const float* x  = (const float*)d_in[0];   // [16384, 512]
    const float* P  = (const float*)d_in[1];   // [512, 16]
    const float* CB = (const float*)d_in[2];   // [8192, 16]
    int* out = (int*)d_out;                    // [16384] int32

    char* ws = (char*)d_ws;
    bf16x8* AfragA = (bf16x8*)(ws + WS_OFF_AFA);
    bf16x8* AfragB = (bf16x8*)(ws + WS_OFF_AFB);
    bf16x8* Bhh    = (bf16x8*)(ws + WS_OFF_BHH);
    bf16x8* B31    = (bf16x8*)(ws + WS_OFF_B31);
    unsigned long long* part = (unsigned long long*)(ws + WS_OFF_PART);
    unsigned* cnt  = (unsigned*)(ws + WS_OFF_CNT);

    k_front<<<PROJ_BLOCKS + PREP_BLOCKS, 256, 0, stream>>>(
        x, P, CB, AfragA, AfragB, Bhh, B31, part, cnt);            // 1152 blocks
    k_scan<<<N_ROWGRP * CODEPARTS, 256, 0, stream>>>(
        AfragA, AfragB, Bhh, B31, part, cnt, out);                 // 1024 blocks
}

// Round 7
// 116.026 us; speedup vs baseline: 2.2661x; 1.0163x over previous
//
#include <hip/hip_runtime.h>
#include <stdint.h>

#define N_ROWS   16384
#define IN_DIM   512
#define CB_DIM   16
#define CB_VOCAB 8192

// ---- front geometry
#define PROJ_BLOCKS 1024                         // 1 row-tile each, 4-wave split-K
#define PREP_BLOCKS 128                          // 4 code-tiles each + part/cnt zero

// ---- scan geometry: fat waves (8 rt x 32 ct), 512 blocks
#define N_CT   (CB_VOCAB / 16)                   // 512 code-tiles
#define CODEPARTS 16
#define CT_PER_PART (N_CT / CODEPARTS)           // 32
#define N_ROWGRP 32                              // 512 rows per rowgrp

// ---- workspace layout (bytes), ~3.2 MB
#define WS_OFF_AFA  0                            // A-frag [A1|A2]: 1 MB
#define WS_OFF_AFB  (1u << 20)                   // A-frag [A1|A3]: 1 MB
#define WS_OFF_BHH  (2u << 20)                   // B-frag [B1;B2]: 512 KB
#define WS_OFF_B31  ((2u << 20) + (512u << 10))  // B-frag [B3;B1]: 512 KB
#define WS_OFF_PART (3u << 20)                   // u64[16384]: 128 KB
#define WS_OFF_CNT  ((3u << 20) + (128u << 10))  // u32[64]

typedef __attribute__((ext_vector_type(8))) short bf16x8;
typedef __attribute__((ext_vector_type(4))) float f32x4;

// monotone float -> uint32 key (order-preserving)
__device__ __forceinline__ unsigned fkey(float f) {
    unsigned u = __float_as_uint(f);
    return (u & 0x80000000u) ? ~u : (u | 0x80000000u);
}

// fp32 -> bf16 bits, round-to-nearest-even
__device__ __forceinline__ unsigned short f2bf(float f) {
    unsigned u = __float_as_uint(f);
    return (unsigned short)((u + 0x7FFFu + ((u >> 16) & 1u)) >> 16);
}
__device__ __forceinline__ float bf2f(unsigned short h) {
    return __uint_as_float(((unsigned)h) << 16);
}

// ---------------- K1: MFMA projection (blocks 0..1023) + prep (1024..1151) --
// BYTE-IDENTICAL to R6 (attribution: this round's delta is all k_scan).
// Block = 1 row-tile; wave w computes a K=128 partial (chunks 4w..4w+3,
// 6 MFMAs each), partials folded through a 4 KB LDS buffer. Each block
// builds the 48 KB P-frag table in its own LDS from P (L2-broadcast-hot);
// prep (CB B-frags + part/cnt zero) rides along as extra blocks.
// LDS 52 KB -> 3 blocks/CU = 12 waves/CU.
__global__ __launch_bounds__(256, 3)
void k_front(const float* __restrict__ x, const float* __restrict__ P,
             const float* __restrict__ CB,
             bf16x8* __restrict__ AfragA, bf16x8* __restrict__ AfragB,
             bf16x8* __restrict__ Bhh, bf16x8* __restrict__ B31,
             unsigned long long* __restrict__ part, unsigned* __restrict__ cnt) {
    __shared__ bf16x8 sPf[3][1024];              // P-frags, 3 levels: 48 KB
    __shared__ __align__(16) float foldb[1024];  // split-K fold / transpose: 4 KB

    const int tid  = threadIdx.x;
    const int wave = tid >> 6;
    const int lane = tid & 63;

    if (blockIdx.x >= PROJ_BLOCKS) {
        // ---- prep path: zero part/cnt, build CB B-frags ----
        const int pb = blockIdx.x - PROJ_BLOCKS;
        if (tid < 128) part[pb * 128 + tid] = 0ull;
        if (pb == 0 && tid < 64) cnt[tid] = 0u;

        const int ct   = pb * 4 + wave;
        const int n    = lane & 15;
        const int quad = lane >> 4;
        const int kh   = (quad & 1) * 8;
        const int lvl  = quad >> 1;
        const int code = ct * 16 + n;

        const float4* b4 = (const float4*)(CB + (size_t)code * CB_DIM + kh);
        float4 a = b4[0], b = b4[1];
        float v[8] = {a.x, a.y, a.z, a.w, b.x, b.y, b.z, b.w};

        bf16x8 shh, s31;
#pragma unroll
        for (int j = 0; j < 8; ++j) {
            float f = v[j];
            unsigned short b1 = f2bf(f);  float r1 = f - bf2f(b1);
            unsigned short b2 = f2bf(r1); float r2 = r1 - bf2f(b2);
            unsigned short b3 = f2bf(r2);
            shh[j] = (short)(lvl ? b2 : b1);
            s31[j] = (short)(lvl ? b1 : b3);
        }
        Bhh[(size_t)ct * 64 + lane] = shh;
        B31[(size_t)ct * 64 + lane] = s31;
        return;
    }

    // ---- Phase A: build P-frags in LDS (slot = chunk*64 + fraglane) ----
#pragma unroll
    for (int s4 = 0; s4 < 4; ++s4) {
        const int s  = tid + s4 * 256;
        const int c  = s >> 6;
        const int l  = s & 63;
        const int n  = l & 15;
        const int kq = l >> 4;
        const int k0 = c * 32 + kq * 8;

        bf16x8 p1, p2, p3;
#pragma unroll
        for (int j = 0; j < 8; ++j) {
            float f = P[(size_t)(k0 + j) * CB_DIM + n];
            unsigned short b1 = f2bf(f);  float r1 = f - bf2f(b1);
            unsigned short b2 = f2bf(r1); float r2 = r1 - bf2f(b2);
            unsigned short b3 = f2bf(r2);
            p1[j] = (short)b1; p2[j] = (short)b2; p3[j] = (short)b3;
        }
        sPf[0][s] = p1; sPf[1][s] = p2; sPf[2][s] = p3;
    }
    __syncthreads();

    // ---- Phase B: split-K proj; wave w covers chunks 4w..4w+3 ----
    const int rt = blockIdx.x;
    const int m  = lane & 15;
    const int kq = lane >> 4;
    const float4* xr = (const float4*)(x + (size_t)(rt * 16 + m) * IN_DIM);

    float4 xf[8];                                // all 8 x-loads issued upfront
#pragma unroll
    for (int i = 0; i < 4; ++i) {
        xf[2 * i]     = xr[(wave * 4 + i) * 8 + kq * 2];
        xf[2 * i + 1] = xr[(wave * 4 + i) * 8 + kq * 2 + 1];
    }

    f32x4 acc1 = {0.f, 0.f, 0.f, 0.f};
    f32x4 acc2 = {0.f, 0.f, 0.f, 0.f};

#pragma unroll
    for (int i = 0; i < 4; ++i) {
        const int c = wave * 4 + i;
        bf16x8 p1 = sPf[0][c * 64 + lane];
        bf16x8 p2 = sPf[1][c * 64 + lane];
        bf16x8 p3 = sPf[2][c * 64 + lane];

        float4 xa = xf[2 * i], xb = xf[2 * i + 1];
        float xs[8] = {xa.x, xa.y, xa.z, xa.w, xb.x, xb.y, xb.z, xb.w};
        bf16x8 a1, a2, a3;
#pragma unroll
        for (int j = 0; j < 8; ++j) {
            float f = xs[j];
            unsigned short b1 = f2bf(f);  float r1 = f - bf2f(b1);
            unsigned short b2 = f2bf(r1); float r2 = r1 - bf2f(b2);
            unsigned short b3 = f2bf(r2);
            a1[j] = (short)b1; a2[j] = (short)b2; a3[j] = (short)b3;
        }

        // terms i+j<=4: (1,1)(2,1)(2,2) chain1; (1,2)(1,3)(3,1) chain2
        acc1 = __builtin_amdgcn_mfma_f32_16x16x32_bf16(a1, p1, acc1, 0, 0, 0);
        acc2 = __builtin_amdgcn_mfma_f32_16x16x32_bf16(a1, p2, acc2, 0, 0, 0);
        acc1 = __builtin_amdgcn_mfma_f32_16x16x32_bf16(a2, p1, acc1, 0, 0, 0);
        acc2 = __builtin_amdgcn_mfma_f32_16x16x32_bf16(a1, p3, acc2, 0, 0, 0);
        acc1 = __builtin_amdgcn_mfma_f32_16x16x32_bf16(a2, p2, acc1, 0, 0, 0);
        acc2 = __builtin_amdgcn_mfma_f32_16x16x32_bf16(a3, p1, acc2, 0, 0, 0);
    }

    *(f32x4*)&foldb[(wave * 64 + lane) * 4] = acc1 + acc2;
    __syncthreads();

    // ---- Phase C (wave 0): fold partials, transpose, split, store ----
    if (wave == 0) {
        f32x4 s0 = *(const f32x4*)&foldb[(0 * 64 + lane) * 4];
        f32x4 s1 = *(const f32x4*)&foldb[(1 * 64 + lane) * 4];
        f32x4 s2 = *(const f32x4*)&foldb[(2 * 64 + lane) * 4];
        f32x4 s3 = *(const f32x4*)&foldb[(3 * 64 + lane) * 4];
        f32x4 sum = ((s0 + s1) + s2) + s3;

        // reads must retire before we overwrite foldb (rule 18 fence)
        asm volatile("s_waitcnt lgkmcnt(0)" ::: "memory");
        __builtin_amdgcn_sched_barrier(0);

        // C layout: lane holds xp[row=(kq*4+r)][col=m] -> transpose [16][20]
#pragma unroll
        for (int r = 0; r < 4; ++r)
            foldb[(kq * 4 + r) * 20 + m] = sum[r];

        asm volatile("s_waitcnt lgkmcnt(0)" ::: "memory");
        __builtin_amdgcn_sched_barrier(0);

        const int kh  = (kq & 1) * 8;
        const int lvl = kq >> 1;
        bf16x8 sa, sb;
#pragma unroll
        for (int j = 0; j < 8; ++j) {
            float f = foldb[m * 20 + kh + j];
            unsigned short b1 = f2bf(f);  float r1 = f - bf2f(b1);
            unsigned short b2 = f2bf(r1); float r2 = r1 - bf2f(b2);
            unsigned short b3 = f2bf(r2);
            sa[j] = (short)(lvl ? b2 : b1);
            sb[j] = (short)(lvl ? b3 : b1);
        }
        AfragA[(size_t)rt * 64 + lane] = sa;
        AfragB[(size_t)rt * 64 + lane] = sb;
    }
}

// ---------------- K2: MFMA sim + argmax + last-block finalize ---------------
// R7: fat waves. grid 512 = 32 rowgrps x 16 codeparts; wave = 8 row-tiles x
// 32 code-tiles. Rationale: k_scan sat at ~38-50 us across 4 micro-tunings
// -- the iteration was too thin (3 loads feeding only 12 MFMA + 48 sel,
// ~150 cyc, barely covering L2 latency; B re-read 64x = 393 MB L2; prologue/
// tail amortized over 16-32 thin iters). With 8 rt/wave each B-frag load
// feeds 24 MFMA + 96 sel (~350 cyc/iter >> L2 latency; depth-1 named-scalar
// prefetch suffices -- rule 20), B traffic halves to 196 MB, prologue/tail
// halve per row. VGPR ~190 (A 64 + best 64 + B 24 + misc);
// __launch_bounds__(256,2) -> cap 256, spill impossible by construction;
// residency 2 blk/CU = 8 waves/CU.
__global__ __launch_bounds__(256, 2)
void k_scan(const bf16x8* __restrict__ AfragA, const bf16x8* __restrict__ AfragB,
            const bf16x8* __restrict__ Bhh, const bf16x8* __restrict__ B31,
            unsigned long long* __restrict__ part, unsigned* __restrict__ cnt,
            int* __restrict__ out) {
    __shared__ int s_done;
    const int codepart = blockIdx.x & (CODEPARTS - 1);
    const int rowgrp   = blockIdx.x >> 4;
    const int wave     = threadIdx.x >> 6;
    const int lane     = threadIdx.x & 63;
    const int n        = lane & 15;
    const int quad     = lane >> 4;
    const int rt_base  = rowgrp * 32 + wave * 8;

    bf16x8 Aa[8], Ab[8];                         // static-indexed only
#pragma unroll
    for (int t = 0; t < 8; ++t) {
        Aa[t] = AfragA[(size_t)(rt_base + t) * 64 + lane];
        Ab[t] = AfragB[(size_t)(rt_base + t) * 64 + lane];
    }

    float bestv[8][4];
    int   bestc[8][4];
#pragma unroll
    for (int t = 0; t < 8; ++t)
#pragma unroll
        for (int r = 0; r < 4; ++r) { bestv[t][r] = -INFINITY; bestc[t][r] = 0; }

    const int ct0 = codepart * CT_PER_PART;
    const bf16x8* p1l = Bhh + (size_t)ct0 * 64 + lane;
    const bf16x8* p1s = Bhh + (size_t)ct0 * 64 + (lane ^ 32);
    const bf16x8* p3l = B31 + (size_t)ct0 * 64 + lane;

    // depth-1 prefetch, named regs only (rule 20): the fat iteration
    // (~350 cyc) is the latency cover.
    bf16x8 c1 = p1l[0], c1s = p1s[0], c3 = p3l[0];

    for (int c = 0; c < CT_PER_PART; ++c) {
        bf16x8 n1, n1s, n3;
        const bool more = (c + 1 < CT_PER_PART);
        if (more) {
            n1  = p1l[(c + 1) * 64];
            n1s = p1s[(c + 1) * 64];
            n3  = p3l[(c + 1) * 64];
        }
#pragma unroll
        for (int t = 0; t < 8; ++t) {
            f32x4 s = __builtin_amdgcn_mfma_f32_16x16x32_bf16(
                          Aa[t], c1, (f32x4){0.f, 0.f, 0.f, 0.f}, 0, 0, 0);
            s = __builtin_amdgcn_mfma_f32_16x16x32_bf16(Aa[t], c1s, s, 0, 0, 0);
            s = __builtin_amdgcn_mfma_f32_16x16x32_bf16(Ab[t], c3,  s, 0, 0, 0);
#pragma unroll
            for (int r = 0; r < 4; ++r) {
                if (s[r] > bestv[t][r]) { bestv[t][r] = s[r]; bestc[t][r] = c; }
            }
        }
        if (more) { c1 = n1; c1s = n1s; c3 = n3; }
    }

    // reduce over the 16 code-class lanes, then device-scope max per row
#pragma unroll
    for (int t = 0; t < 8; ++t) {
#pragma unroll
        for (int r = 0; r < 4; ++r) {
            unsigned code = (unsigned)(codepart * (CT_PER_PART * 16) +
                                       bestc[t][r] * 16 + n);
            unsigned long long packed =
                ((unsigned long long)fkey(bestv[t][r]) << 32) |
                (unsigned long long)(0xFFFFFFFFu - code);
#pragma unroll
            for (int mk = 1; mk <= 8; mk <<= 1) {
                unsigned long long o = __shfl_xor(packed, mk, 64);
                packed = (o > packed) ? o : packed;
            }
            if (n == 0) {
                int row = (rt_base + t) * 16 + quad * 4 + r;
                atomicMax(&part[row], packed);
            }
        }
    }

    // __syncthreads drains vmcnt -> all this block's atomics are complete
    __syncthreads();
    if (threadIdx.x == 0)
        s_done = (atomicAdd(&cnt[rowgrp], 1u) == (unsigned)(CODEPARTS - 1));
    __syncthreads();

    if (s_done) {
#pragma unroll
        for (int i = 0; i < 2; ++i) {
            int row = rowgrp * 512 + i * 256 + threadIdx.x;
            unsigned long long v = atomicAdd(&part[row], 0ull); // coherent read
            out[row] = (int)(0xFFFFFFFFu - (unsigned)(v & 0xFFFFFFFFull));
        }
    }
}

extern "C" void kernel_launch(void* const* d_in, const int* in_sizes, int n_in,
                              void* d_out, int out_size, void* d_ws, size_t ws_size,
                              hipStream_t stream) {
    const float* x  = (const float*)d_in[0];   // [16384, 512]
    const float* P  = (const float*)d_in[1];   // [512, 16]
    const float* CB = (const float*)d_in[2];   // [8192, 16]
    int* out = (int*)d_out;                    // [16384] int32

    char* ws = (char*)d_ws;
    bf16x8* AfragA = (bf16x8*)(ws + WS_OFF_AFA);
    bf16x8* AfragB = (bf16x8*)(ws + WS_OFF_AFB);
    bf16x8* Bhh    = (bf16x8*)(ws + WS_OFF_BHH);
    bf16x8* B31    = (bf16x8*)(ws + WS_OFF_B31);
    unsigned long long* part = (unsigned long long*)(ws + WS_OFF_PART);
    unsigned* cnt  = (unsigned*)(ws + WS_OFF_CNT);

    k_front<<<PROJ_BLOCKS + PREP_BLOCKS, 256, 0, stream>>>(
        x, P, CB, AfragA, AfragB, Bhh, B31, part, cnt);            // 1152 blocks
    k_scan<<<N_ROWGRP * CODEPARTS, 256, 0, stream>>>(
        AfragA, AfragB, Bhh, B31, part, cnt, out);                 // 512 blocks
}

// Round 8
// 112.603 us; speedup vs baseline: 2.3350x; 1.0304x over previous
//
#include <hip/hip_runtime.h>
#include <stdint.h>

#define N_ROWS   16384
#define IN_DIM   512
#define CB_DIM   16
#define CB_VOCAB 8192

// ---- front geometry
#define PROJ_BLOCKS 1024                         // 1 row-tile each, 4-wave split-K
#define PREP_BLOCKS 128                          // 4 code-tiles each + part/cnt zero

// ---- scan geometry (R0's measured-38.8us text, verbatim)
#define N_CT   (CB_VOCAB / 16)                   // 512 code-tiles
#define CODEPARTS 16
#define CT_PER_PART (N_CT / CODEPARTS)           // 32
#define N_ROWGRP 64                              // 256 rows per rowgrp

// ---- workspace layout (bytes), ~3.2 MB
#define WS_OFF_AFA  0                            // A-frag [A1|A2]: 1 MB
#define WS_OFF_AFB  (1u << 20)                   // A-frag [A1|A3]: 1 MB
#define WS_OFF_BHH  (2u << 20)                   // B-frag [B1;B2]: 512 KB
#define WS_OFF_B31  ((2u << 20) + (512u << 10))  // B-frag [B3;B1]: 512 KB
#define WS_OFF_PART (3u << 20)                   // u64[16384]: 128 KB
#define WS_OFF_CNT  ((3u << 20) + (128u << 10))  // u32[64]

typedef __attribute__((ext_vector_type(8))) short bf16x8;
typedef __attribute__((ext_vector_type(4))) float f32x4;

// monotone float -> uint32 key (order-preserving)
__device__ __forceinline__ unsigned fkey(float f) {
    unsigned u = __float_as_uint(f);
    return (u & 0x80000000u) ? ~u : (u | 0x80000000u);
}

// fp32 -> bf16 bits, round-to-nearest-even
__device__ __forceinline__ unsigned short f2bf(float f) {
    unsigned u = __float_as_uint(f);
    return (unsigned short)((u + 0x7FFFu + ((u >> 16) & 1u)) >> 16);
}
__device__ __forceinline__ float bf2f(unsigned short h) {
    return __uint_as_float(((unsigned)h) << 16);
}

// ---------------- K1: MFMA projection (blocks 0..1023) + prep (1024..1151) --
// BYTE-IDENTICAL to R6/R7 (inferred measured 38.9 us via R5 algebra -- 2x
// better than the old VALU front's 75.6). This round's delta is all k_scan.
__global__ __launch_bounds__(256, 3)
void k_front(const float* __restrict__ x, const float* __restrict__ P,
             const float* __restrict__ CB,
             bf16x8* __restrict__ AfragA, bf16x8* __restrict__ AfragB,
             bf16x8* __restrict__ Bhh, bf16x8* __restrict__ B31,
             unsigned long long* __restrict__ part, unsigned* __restrict__ cnt) {
    __shared__ bf16x8 sPf[3][1024];              // P-frags, 3 levels: 48 KB
    __shared__ __align__(16) float foldb[1024];  // split-K fold / transpose: 4 KB

    const int tid  = threadIdx.x;
    const int wave = tid >> 6;
    const int lane = tid & 63;

    if (blockIdx.x >= PROJ_BLOCKS) {
        // ---- prep path: zero part/cnt, build CB B-frags ----
        const int pb = blockIdx.x - PROJ_BLOCKS;
        if (tid < 128) part[pb * 128 + tid] = 0ull;
        if (pb == 0 && tid < 64) cnt[tid] = 0u;

        const int ct   = pb * 4 + wave;
        const int n    = lane & 15;
        const int quad = lane >> 4;
        const int kh   = (quad & 1) * 8;
        const int lvl  = quad >> 1;
        const int code = ct * 16 + n;

        const float4* b4 = (const float4*)(CB + (size_t)code * CB_DIM + kh);
        float4 a = b4[0], b = b4[1];
        float v[8] = {a.x, a.y, a.z, a.w, b.x, b.y, b.z, b.w};

        bf16x8 shh, s31;
#pragma unroll
        for (int j = 0; j < 8; ++j) {
            float f = v[j];
            unsigned short b1 = f2bf(f);  float r1 = f - bf2f(b1);
            unsigned short b2 = f2bf(r1); float r2 = r1 - bf2f(b2);
            unsigned short b3 = f2bf(r2);
            shh[j] = (short)(lvl ? b2 : b1);
            s31[j] = (short)(lvl ? b1 : b3);
        }
        Bhh[(size_t)ct * 64 + lane] = shh;
        B31[(size_t)ct * 64 + lane] = s31;
        return;
    }

    // ---- Phase A: build P-frags in LDS (slot = chunk*64 + fraglane) ----
#pragma unroll
    for (int s4 = 0; s4 < 4; ++s4) {
        const int s  = tid + s4 * 256;
        const int c  = s >> 6;
        const int l  = s & 63;
        const int n  = l & 15;
        const int kq = l >> 4;
        const int k0 = c * 32 + kq * 8;

        bf16x8 p1, p2, p3;
#pragma unroll
        for (int j = 0; j < 8; ++j) {
            float f = P[(size_t)(k0 + j) * CB_DIM + n];
            unsigned short b1 = f2bf(f);  float r1 = f - bf2f(b1);
            unsigned short b2 = f2bf(r1); float r2 = r1 - bf2f(b2);
            unsigned short b3 = f2bf(r2);
            p1[j] = (short)b1; p2[j] = (short)b2; p3[j] = (short)b3;
        }
        sPf[0][s] = p1; sPf[1][s] = p2; sPf[2][s] = p3;
    }
    __syncthreads();

    // ---- Phase B: split-K proj; wave w covers chunks 4w..4w+3 ----
    const int rt = blockIdx.x;
    const int m  = lane & 15;
    const int kq = lane >> 4;
    const float4* xr = (const float4*)(x + (size_t)(rt * 16 + m) * IN_DIM);

    float4 xf[8];                                // all 8 x-loads issued upfront
#pragma unroll
    for (int i = 0; i < 4; ++i) {
        xf[2 * i]     = xr[(wave * 4 + i) * 8 + kq * 2];
        xf[2 * i + 1] = xr[(wave * 4 + i) * 8 + kq * 2 + 1];
    }

    f32x4 acc1 = {0.f, 0.f, 0.f, 0.f};
    f32x4 acc2 = {0.f, 0.f, 0.f, 0.f};

#pragma unroll
    for (int i = 0; i < 4; ++i) {
        const int c = wave * 4 + i;
        bf16x8 p1 = sPf[0][c * 64 + lane];
        bf16x8 p2 = sPf[1][c * 64 + lane];
        bf16x8 p3 = sPf[2][c * 64 + lane];

        float4 xa = xf[2 * i], xb = xf[2 * i + 1];
        float xs[8] = {xa.x, xa.y, xa.z, xa.w, xb.x, xb.y, xb.z, xb.w};
        bf16x8 a1, a2, a3;
#pragma unroll
        for (int j = 0; j < 8; ++j) {
            float f = xs[j];
            unsigned short b1 = f2bf(f);  float r1 = f - bf2f(b1);
            unsigned short b2 = f2bf(r1); float r2 = r1 - bf2f(b2);
            unsigned short b3 = f2bf(r2);
            a1[j] = (short)b1; a2[j] = (short)b2; a3[j] = (short)b3;
        }

        // terms i+j<=4: (1,1)(2,1)(2,2) chain1; (1,2)(1,3)(3,1) chain2
        acc1 = __builtin_amdgcn_mfma_f32_16x16x32_bf16(a1, p1, acc1, 0, 0, 0);
        acc2 = __builtin_amdgcn_mfma_f32_16x16x32_bf16(a1, p2, acc2, 0, 0, 0);
        acc1 = __builtin_amdgcn_mfma_f32_16x16x32_bf16(a2, p1, acc1, 0, 0, 0);
        acc2 = __builtin_amdgcn_mfma_f32_16x16x32_bf16(a1, p3, acc2, 0, 0, 0);
        acc1 = __builtin_amdgcn_mfma_f32_16x16x32_bf16(a2, p2, acc1, 0, 0, 0);
        acc2 = __builtin_amdgcn_mfma_f32_16x16x32_bf16(a3, p1, acc2, 0, 0, 0);
    }

    *(f32x4*)&foldb[(wave * 64 + lane) * 4] = acc1 + acc2;
    __syncthreads();

    // ---- Phase C (wave 0): fold partials, transpose, split, store ----
    if (wave == 0) {
        f32x4 s0 = *(const f32x4*)&foldb[(0 * 64 + lane) * 4];
        f32x4 s1 = *(const f32x4*)&foldb[(1 * 64 + lane) * 4];
        f32x4 s2 = *(const f32x4*)&foldb[(2 * 64 + lane) * 4];
        f32x4 s3 = *(const f32x4*)&foldb[(3 * 64 + lane) * 4];
        f32x4 sum = ((s0 + s1) + s2) + s3;

        // reads must retire before we overwrite foldb (rule 18 fence)
        asm volatile("s_waitcnt lgkmcnt(0)" ::: "memory");
        __builtin_amdgcn_sched_barrier(0);

        // C layout: lane holds xp[row=(kq*4+r)][col=m] -> transpose [16][20]
#pragma unroll
        for (int r = 0; r < 4; ++r)
            foldb[(kq * 4 + r) * 20 + m] = sum[r];

        asm volatile("s_waitcnt lgkmcnt(0)" ::: "memory");
        __builtin_amdgcn_sched_barrier(0);

        const int kh  = (kq & 1) * 8;
        const int lvl = kq >> 1;
        bf16x8 sa, sb;
#pragma unroll
        for (int j = 0; j < 8; ++j) {
            float f = foldb[m * 20 + kh + j];
            unsigned short b1 = f2bf(f);  float r1 = f - bf2f(b1);
            unsigned short b2 = f2bf(r1); float r2 = r1 - bf2f(b2);
            unsigned short b3 = f2bf(r2);
            sa[j] = (short)(lvl ? b2 : b1);
            sb[j] = (short)(lvl ? b3 : b1);
        }
        AfragA[(size_t)rt * 64 + lane] = sa;
        AfragB[(size_t)rt * 64 + lane] = sb;
    }
}

// ---------------- K2: MFMA sim + argmax + last-block finalize ---------------
// R8: VERBATIM restore of R0's measured-38.8us scan. R6's depth-2 named
// prefetch (+48 live VGPR at (256,4)) crossed the 128-VGPR cliff -> ~79 us;
// R7's fat-wave carried ~77. This text is the known-good register budget
// (~80 live, no spill): grid 1024 = 64 rowgrps x 16 codeparts, wave = 4
// row-tiles x 32 code-tiles, depth-1 SW-pipelined B loads, 3 chained bf16
// MFMAs per tile. Cross-block argmax via device-scope atomicMax(u64); the
// 16th block to finish a rowgrp decodes part[] -> out[].
__global__ __launch_bounds__(256, 4)
void k_scan(const bf16x8* __restrict__ AfragA, const bf16x8* __restrict__ AfragB,
            const bf16x8* __restrict__ Bhh, const bf16x8* __restrict__ B31,
            unsigned long long* __restrict__ part, unsigned* __restrict__ cnt,
            int* __restrict__ out) {
    __shared__ int s_done;
    const int codepart = blockIdx.x & (CODEPARTS - 1);
    const int rowgrp   = blockIdx.x >> 4;
    const int wave     = threadIdx.x >> 6;
    const int lane     = threadIdx.x & 63;
    const int n        = lane & 15;
    const int quad     = lane >> 4;
    const int rt_base  = rowgrp * 16 + wave * 4;

    bf16x8 Aa[4], Ab[4];
#pragma unroll
    for (int t = 0; t < 4; ++t) {
        Aa[t] = AfragA[(size_t)(rt_base + t) * 64 + lane];
        Ab[t] = AfragB[(size_t)(rt_base + t) * 64 + lane];
    }

    float bestv[4][4];
    int   bestc[4][4];
#pragma unroll
    for (int t = 0; t < 4; ++t)
#pragma unroll
        for (int r = 0; r < 4; ++r) { bestv[t][r] = -INFINITY; bestc[t][r] = 0; }

    const int ct0 = codepart * CT_PER_PART;
    size_t ib = (size_t)ct0 * 64;
    bf16x8 nb1  = Bhh[ib + lane];
    bf16x8 nb1s = Bhh[ib + (lane ^ 32)];
    bf16x8 nb3  = B31[ib + lane];

    for (int c = 0; c < CT_PER_PART; ++c) {
        bf16x8 b1 = nb1, b1s = nb1s, b3 = nb3;
        if (c + 1 < CT_PER_PART) {
            size_t ibn = (size_t)(ct0 + c + 1) * 64;
            nb1  = Bhh[ibn + lane];
            nb1s = Bhh[ibn + (lane ^ 32)];
            nb3  = B31[ibn + lane];
        }
#pragma unroll
        for (int t = 0; t < 4; ++t) {
            f32x4 s = __builtin_amdgcn_mfma_f32_16x16x32_bf16(
                          Aa[t], b1, (f32x4){0.f, 0.f, 0.f, 0.f}, 0, 0, 0);
            s = __builtin_amdgcn_mfma_f32_16x16x32_bf16(Aa[t], b1s, s, 0, 0, 0);
            s = __builtin_amdgcn_mfma_f32_16x16x32_bf16(Ab[t], b3,  s, 0, 0, 0);
#pragma unroll
            for (int r = 0; r < 4; ++r) {
                if (s[r] > bestv[t][r]) { bestv[t][r] = s[r]; bestc[t][r] = c; }
            }
        }
    }

    // reduce over the 16 code-class lanes, then device-scope max per row
#pragma unroll
    for (int t = 0; t < 4; ++t) {
#pragma unroll
        for (int r = 0; r < 4; ++r) {
            unsigned code = (unsigned)(codepart * 512 + bestc[t][r] * 16 + n);
            unsigned long long packed =
                ((unsigned long long)fkey(bestv[t][r]) << 32) |
                (unsigned long long)(0xFFFFFFFFu - code);
#pragma unroll
            for (int mk = 1; mk <= 8; mk <<= 1) {
                unsigned long long o = __shfl_xor(packed, mk, 64);
                packed = (o > packed) ? o : packed;
            }
            if (n == 0) {
                int row = (rt_base + t) * 16 + quad * 4 + r;
                atomicMax(&part[row], packed);
            }
        }
    }

    // __syncthreads drains vmcnt -> all this block's atomics are complete
    __syncthreads();
    if (threadIdx.x == 0)
        s_done = (atomicAdd(&cnt[rowgrp], 1u) == (unsigned)(CODEPARTS - 1));
    __syncthreads();

    if (s_done) {
        int row = rowgrp * 256 + threadIdx.x;
        unsigned long long v = atomicAdd(&part[row], 0ull);   // coherent read
        out[row] = (int)(0xFFFFFFFFu - (unsigned)(v & 0xFFFFFFFFull));
    }
}

extern "C" void kernel_launch(void* const* d_in, const int* in_sizes, int n_in,
                              void* d_out, int out_size, void* d_ws, size_t ws_size,
                              hipStream_t stream) {
    const float* x  = (const float*)d_in[0];   // [16384, 512]
    const float* P  = (const float*)d_in[1];   // [512, 16]
    const float* CB = (const float*)d_in[2];   // [8192, 16]
    int* out = (int*)d_out;                    // [16384] int32

    char* ws = (char*)d_ws;
    bf16x8* AfragA = (bf16x8*)(ws + WS_OFF_AFA);
    bf16x8* AfragB = (bf16x8*)(ws + WS_OFF_AFB);
    bf16x8* Bhh    = (bf16x8*)(ws + WS_OFF_BHH);
    bf16x8* B31    = (bf16x8*)(ws + WS_OFF_B31);
    unsigned long long* part = (unsigned long long*)(ws + WS_OFF_PART);
    unsigned* cnt  = (unsigned*)(ws + WS_OFF_CNT);

    k_front<<<PROJ_BLOCKS + PREP_BLOCKS, 256, 0, stream>>>(
        x, P, CB, AfragA, AfragB, Bhh, B31, part, cnt);            // 1152 blocks
    k_scan<<<N_ROWGRP * CODEPARTS, 256, 0, stream>>>(
        AfragA, AfragB, Bhh, B31, part, cnt, out);                 // 1024 blocks
}